// Round 1
// baseline (270.659 us; speedup 1.0000x reference)
//
#include <hip/hip_runtime.h>

#define NN 100
#define CC 256
#define KK 3
#define NKK 103

typedef __bf16 bf16;
typedef __bf16 bf16x8 __attribute__((ext_vector_type(8)));
typedef float f32x4 __attribute__((ext_vector_type(4)));

#define LDA 40     // phase-A staging row stride (32 + 8 pad): 2-way bank alias only
#define LDP 136    // pw / depthT k-stride (128 + 8 pad): 2-way bank alias only

__global__ __launch_bounds__(256, 2)
void dysepconv_fused(const float* __restrict__ query,
                     const float* __restrict__ value,
                     const float* __restrict__ W,
                     const float* __restrict__ bwl,
                     const float* __restrict__ gamma,
                     const float* __restrict__ beta,
                     float* __restrict__ out)
{
    // LDS: 30464 + 1200 + 17920 + 3584 + 896 = 54064 B  -> 2 blocks/CU
    __shared__ bf16 PW[112 * LDP];              // pw (A2 operand), zero-padded in m>=100, n>=100
    __shared__ float DW[NN][3];                 // conv weights, fp32
    __shared__ __align__(16) bf16 SCR[8960];    // A: Abuf(112x40)+Bbuf(112x40) | C: depthT(64x136)
    __shared__ float RP[4][112][2];             // per-wave LN partials
    __shared__ float RS[112][2];                // mean, rstd per row

    const int t    = threadIdx.x;
    const int w    = t >> 6;          // wave 0..3
    const int lane = t & 63;
    const int ln16 = lane & 15;
    const int g    = lane >> 4;       // 16-lane group 0..3
    const int hi8  = g * 8;
    const int b    = blockIdx.x;

    bf16* Abuf = SCR;
    bf16* Bbuf = SCR + 112 * LDA;
    bf16* DT   = SCR;                 // 64 x LDP

    // zero pw buffer (padding rows/cols must be exact 0.0 for GEMM2 K-padding)
    {
        unsigned int* p = (unsigned int*)PW;
        for (int i = t; i < 112 * LDP / 2; i += 256) p[i] = 0u;
    }

    const float* qb = query + (size_t)b * NN * CC;
    const float* vb = value + (size_t)b * NN * CC;

    // ---------------- Phase A: dy = query @ W + bias (bf16 MFMA) ----------------
    f32x4 acc1[2][7];
    #pragma unroll
    for (int jj = 0; jj < 2; ++jj)
        #pragma unroll
        for (int I = 0; I < 7; ++I) acc1[jj][I] = (f32x4){0.f, 0.f, 0.f, 0.f};

    for (int kc = 0; kc < 8; ++kc) {
        const int k0 = kc * 32;
        __syncthreads();
        // stage query chunk -> bf16, rows >=100 zeroed
        for (int idx = t; idx < 112 * 32; idx += 256) {
            int r = idx >> 5, j = idx & 31;
            float v = (r < NN) ? qb[r * CC + k0 + j] : 0.f;
            Abuf[r * LDA + j] = (bf16)v;
        }
        // stage W transposed -> Bbuf[kappa][kc], cols >=103 zeroed
        for (int idx = t; idx < 112 * 32; idx += 256) {
            int ci = idx / 112, kp = idx % 112;
            float v = (kp < NKK) ? W[(k0 + ci) * NKK + kp] : 0.f;
            Bbuf[kp * LDA + ci] = (bf16)v;
        }
        __syncthreads();

        bf16x8 af[7];
        #pragma unroll
        for (int I = 0; I < 7; ++I)
            af[I] = *(const bf16x8*)&Abuf[(I * 16 + ln16) * LDA + hi8];
        #pragma unroll
        for (int jj = 0; jj < 2; ++jj) {
            int J = w + jj * 4;
            if (J < 7) {
                bf16x8 bf = *(const bf16x8*)&Bbuf[(J * 16 + ln16) * LDA + hi8];
                #pragma unroll
                for (int I = 0; I < 7; ++I)
                    acc1[jj][I] = __builtin_amdgcn_mfma_f32_16x16x32_bf16(af[I], bf, acc1[jj][I], 0, 0, 0);
            }
        }
    }
    __syncthreads();

    // epilogue A: + bias, split into DW (fp32) and PW (bf16)
    #pragma unroll
    for (int jj = 0; jj < 2; ++jj) {
        int J = w + jj * 4;
        if (J < 7) {
            int kap = J * 16 + ln16;
            float bw = (kap < NKK) ? bwl[kap] : 0.f;
            #pragma unroll
            for (int I = 0; I < 7; ++I) {
                #pragma unroll
                for (int r = 0; r < 4; ++r) {
                    int n = I * 16 + g * 4 + r;
                    if (n < NN && kap < NKK) {
                        float v = acc1[jj][I][r] + bw;
                        if (kap < KK) DW[n][kap] = v;
                        else          PW[n * LDP + (kap - KK)] = (bf16)v;
                    }
                }
            }
        }
    }

    // ---------------- Phase B/C: depth conv + out = pw @ depth ----------------
    f32x4 acc2[4][7];
    #pragma unroll
    for (int q = 0; q < 4; ++q)
        #pragma unroll
        for (int I = 0; I < 7; ++I) acc2[q][I] = (f32x4){0.f, 0.f, 0.f, 0.f};

    #pragma unroll
    for (int q = 0; q < 4; ++q) {
        __syncthreads();   // SCR reuse safe; PW/DW visible on first iter
        const int c = q * 64 + lane;
        for (int i = 0; i < 32; ++i) {
            int m = w + i * 4;          // wave-uniform m
            float d = 0.f;
            if (m < NN) {
                const float* vr = vb + m * CC;
                float vm1 = (c > 0)   ? vr[c - 1] : 0.f;
                float v0  = vr[c];
                float vp1 = (c < 255) ? vr[c + 1] : 0.f;
                d = DW[m][0] * vm1 + DW[m][1] * v0 + DW[m][2] * vp1;
                d = fmaxf(d, 0.f);
            }
            DT[lane * LDP + m] = (bf16)d;   // transposed store (B-operand layout)
        }
        __syncthreads();
        #pragma unroll
        for (int ks = 0; ks < 4; ++ks) {
            const int ko = ks * 32 + hi8;
            bf16x8 bf = *(const bf16x8*)&DT[(w * 16 + ln16) * LDP + ko];
            #pragma unroll
            for (int I = 0; I < 7; ++I) {
                bf16x8 af = *(const bf16x8*)&PW[(I * 16 + ln16) * LDP + ko];
                acc2[q][I] = __builtin_amdgcn_mfma_f32_16x16x32_bf16(af, bf, acc2[q][I], 0, 0, 0);
            }
        }
    }

    // ---------------- Phase D: LayerNorm + store ----------------
    #pragma unroll
    for (int I = 0; I < 7; ++I) {
        #pragma unroll
        for (int r = 0; r < 4; ++r) {
            float a0 = acc2[0][I][r], a1 = acc2[1][I][r], a2 = acc2[2][I][r], a3 = acc2[3][I][r];
            float s1 = a0 + a1 + a2 + a3;
            float s2 = a0 * a0 + a1 * a1 + a2 * a2 + a3 * a3;
            #pragma unroll
            for (int mk = 1; mk < 16; mk <<= 1) {
                s1 += __shfl_xor(s1, mk);
                s2 += __shfl_xor(s2, mk);
            }
            if (ln16 == 0) {
                int n = I * 16 + g * 4 + r;
                RP[w][n][0] = s1;
                RP[w][n][1] = s2;
            }
        }
    }
    __syncthreads();
    if (t < 112) {
        float S1 = RP[0][t][0] + RP[1][t][0] + RP[2][t][0] + RP[3][t][0];
        float S2 = RP[0][t][1] + RP[1][t][1] + RP[2][t][1] + RP[3][t][1];
        float mu  = S1 * (1.f / 256.f);
        float var = S2 * (1.f / 256.f) - mu * mu;
        RS[t][0] = mu;
        RS[t][1] = rsqrtf(fmaxf(var, 0.f) + 1e-5f);
    }
    __syncthreads();

    float gm[4], bt[4];
    int   cq[4];
    #pragma unroll
    for (int q = 0; q < 4; ++q) {
        cq[q] = (q * 4 + w) * 16 + ln16;
        gm[q] = gamma[cq[q]];
        bt[q] = beta[cq[q]];
    }
    float* ob = out + (size_t)b * NN * CC;
    #pragma unroll
    for (int I = 0; I < 7; ++I) {
        #pragma unroll
        for (int r = 0; r < 4; ++r) {
            int n = I * 16 + g * 4 + r;
            if (n < NN) {
                float mu = RS[n][0], rs = RS[n][1];
                #pragma unroll
                for (int q = 0; q < 4; ++q)
                    ob[n * CC + cq[q]] = (acc2[q][I][r] - mu) * rs * gm[q] + bt[q];
            }
        }
    }
}

extern "C" void kernel_launch(void* const* d_in, const int* in_sizes, int n_in,
                              void* d_out, int out_size, void* d_ws, size_t ws_size,
                              hipStream_t stream) {
    const float* query = (const float*)d_in[0];
    const float* value = (const float*)d_in[1];
    const float* W     = (const float*)d_in[2];
    const float* bwl   = (const float*)d_in[3];
    const float* gamma = (const float*)d_in[4];
    const float* beta  = (const float*)d_in[5];
    dysepconv_fused<<<dim3(512), dim3(256), 0, stream>>>(query, value, W, bwl, gamma, beta, (float*)d_out);
}

// Round 2
// 253.987 us; speedup vs baseline: 1.0656x; 1.0656x over previous
//
#include <hip/hip_runtime.h>

#define NN 100
#define CC 256
#define NKK 103
#define LDP 136   // PW row stride (128 + 8 pad)

typedef __bf16 bf16;
typedef __bf16 bf16x8 __attribute__((ext_vector_type(8)));
typedef float f32x4 __attribute__((ext_vector_type(4)));

__global__ __launch_bounds__(512, 4)
void dysepconv_fused(const float* __restrict__ query,
                     const float* __restrict__ value,
                     const float* __restrict__ W,
                     const float* __restrict__ bwl,
                     const float* __restrict__ gamma,
                     const float* __restrict__ beta,
                     float* __restrict__ out)
{
    // LDS: 30464 + 1200 + 7168 + 896 = 39728 B (no staging buffers at all)
    __shared__ bf16 PW[112 * LDP];   // pw, A-operand of GEMM2; zero-padded n>=100, m>=100
    __shared__ float DW[NN][3];      // conv weights fp32
    __shared__ float RP[8][112][2];  // per-wave LN partials
    __shared__ float RS[112][2];     // mean, rstd

    const int t    = threadIdx.x;
    const int w    = t >> 6;        // wave 0..7
    const int lane = t & 63;
    const int ln16 = lane & 15;
    const int g    = lane >> 4;     // 0..3
    const int hi8  = g * 8;
    const int b    = blockIdx.x;

    // zero PW (padding must be exact 0.0); no other LDS init needed
    for (int i = t; i < 112 * LDP / 2; i += 512) ((unsigned*)PW)[i] = 0u;
    __syncthreads();   // init-zero complete before epilogue-A overwrites valid region

    const float* qb = query + (size_t)b * NN * CC;
    const float* vb = value + (size_t)b * NN * CC;

    // ---------------- Phase A: dy = query @ W + b, no LDS, no barriers ----------------
    // wave w owns N-tile J=w (kap = w*16+ln16); wave 7 idles here
    if (w < 7) {
        f32x4 acc1[7];
        #pragma unroll
        for (int I = 0; I < 7; ++I) acc1[I] = (f32x4){0.f, 0.f, 0.f, 0.f};
        const int kap = w * 16 + ln16;

        #pragma unroll
        for (int ks = 0; ks < 8; ++ks) {
            const int k0 = ks * 32 + hi8;
            // B fragment: W^T[kap][k0..k0+8] gathered from W (L2-hot, 4x64B segments/inst)
            bf16x8 bv;
            #pragma unroll
            for (int j = 0; j < 8; ++j) {
                float x = (kap < NKK) ? W[(k0 + j) * NKK + kap] : 0.f;
                bv[j] = (bf16)x;
            }
            #pragma unroll
            for (int I = 0; I < 7; ++I) {
                int row = I * 16 + ln16;
                f32x4 a0 = (f32x4){0.f,0.f,0.f,0.f}, a1 = (f32x4){0.f,0.f,0.f,0.f};
                if (row < NN) {   // rows >=100 masked (avoids OOB at b=511); garbage rows discarded anyway
                    a0 = *(const f32x4*)(qb + row * CC + k0);
                    a1 = *(const f32x4*)(qb + row * CC + k0 + 4);
                }
                bf16x8 av;
                #pragma unroll
                for (int j = 0; j < 4; ++j) { av[j] = (bf16)a0[j]; av[4 + j] = (bf16)a1[j]; }
                acc1[I] = __builtin_amdgcn_mfma_f32_16x16x32_bf16(av, bv, acc1[I], 0, 0, 0);
            }
        }

        // epilogue A: + bias, split into DW (fp32) and PW (bf16)
        float bw = (kap < NKK) ? bwl[kap] : 0.f;
        #pragma unroll
        for (int I = 0; I < 7; ++I) {
            #pragma unroll
            for (int r = 0; r < 4; ++r) {
                int n = I * 16 + g * 4 + r;
                if (n < NN && kap < NKK) {
                    float v = acc1[I][r] + bw;
                    if (kap < 3) DW[n][kap] = v;
                    else         PW[n * LDP + (kap - 3)] = (bf16)v;
                }
            }
        }
    }
    __syncthreads();   // PW/DW visible

    // ---------------- Phase B/C: conv in B-fragment register layout + GEMM2 ----------------
    // wave w owns c-subtiles {w, w+8}: c = w*16+ln16 (+128). Conv output lands directly in
    // B-operand layout (n=ln16<->c, k=g*8+j<->m): no LDS transpose, no barriers.
    f32x4 acc2[2][7];
    #pragma unroll
    for (int st = 0; st < 2; ++st)
        #pragma unroll
        for (int I = 0; I < 7; ++I) acc2[st][I] = (f32x4){0.f, 0.f, 0.f, 0.f};

    const int c0 = w * 16 + ln16;
    #pragma unroll
    for (int ks = 0; ks < 4; ++ks) {
        bf16x8 af[7];   // PW fragments, shared by both c-subtiles
        #pragma unroll
        for (int I = 0; I < 7; ++I)
            af[I] = *(const bf16x8*)&PW[(I * 16 + ln16) * LDP + ks * 32 + hi8];
        #pragma unroll
        for (int st = 0; st < 2; ++st) {
            const int c = c0 + st * 128;
            bf16x8 dv;
            #pragma unroll
            for (int j = 0; j < 8; ++j) {
                int  m  = ks * 32 + hi8 + j;
                bool mv = (m < NN);
                int  mc = mv ? m : (NN - 1);     // clamp for safe LDS read
                float v0 = mv ? vb[m * CC + c] : 0.f;
                float vm1 = __shfl(v0, (lane - 1) & 63);
                float vp1 = __shfl(v0, (lane + 1) & 63);
                if (ln16 == 0)  vm1 = (mv && c > 0)      ? vb[m * CC + c - 1] : 0.f;
                if (ln16 == 15) vp1 = (mv && c < CC - 1) ? vb[m * CC + c + 1] : 0.f;
                float d = DW[mc][0] * vm1 + DW[mc][1] * v0 + DW[mc][2] * vp1;
                d = fmaxf(d, 0.f);
                dv[j] = (bf16)(mv ? d : 0.f);
            }
            #pragma unroll
            for (int I = 0; I < 7; ++I)
                acc2[st][I] = __builtin_amdgcn_mfma_f32_16x16x32_bf16(af[I], dv, acc2[st][I], 0, 0, 0);
        }
    }

    // ---------------- Phase D: LayerNorm + store ----------------
    #pragma unroll
    for (int I = 0; I < 7; ++I) {
        #pragma unroll
        for (int r = 0; r < 4; ++r) {
            float a = acc2[0][I][r], e = acc2[1][I][r];
            float s1 = a + e, s2 = a * a + e * e;
            #pragma unroll
            for (int mk = 1; mk < 16; mk <<= 1) {
                s1 += __shfl_xor(s1, mk);
                s2 += __shfl_xor(s2, mk);
            }
            if (ln16 == 0) {
                int n = I * 16 + g * 4 + r;
                RP[w][n][0] = s1;
                RP[w][n][1] = s2;
            }
        }
    }
    __syncthreads();
    if (t < 112) {
        float S1 = 0.f, S2 = 0.f;
        #pragma unroll
        for (int wi = 0; wi < 8; ++wi) { S1 += RP[wi][t][0]; S2 += RP[wi][t][1]; }
        float mu  = S1 * (1.f / 256.f);
        float var = S2 * (1.f / 256.f) - mu * mu;
        RS[t][0] = mu;
        RS[t][1] = rsqrtf(fmaxf(var, 0.f) + 1e-5f);
    }
    __syncthreads();

    const float gm0 = gamma[c0], gm1 = gamma[c0 + 128];
    const float bt0 = beta[c0],  bt1 = beta[c0 + 128];
    float* ob = out + (size_t)b * NN * CC;
    #pragma unroll
    for (int I = 0; I < 7; ++I) {
        #pragma unroll
        for (int r = 0; r < 4; ++r) {
            int n = I * 16 + g * 4 + r;
            if (n < NN) {
                float mu = RS[n][0], rs = RS[n][1];
                ob[n * CC + c0]       = (acc2[0][I][r] - mu) * rs * gm0 + bt0;
                ob[n * CC + c0 + 128] = (acc2[1][I][r] - mu) * rs * gm1 + bt1;
            }
        }
    }
}

extern "C" void kernel_launch(void* const* d_in, const int* in_sizes, int n_in,
                              void* d_out, int out_size, void* d_ws, size_t ws_size,
                              hipStream_t stream) {
    const float* query = (const float*)d_in[0];
    const float* value = (const float*)d_in[1];
    const float* W     = (const float*)d_in[2];
    const float* bwl   = (const float*)d_in[3];
    const float* gamma = (const float*)d_in[4];
    const float* beta  = (const float*)d_in[5];
    dysepconv_fused<<<dim3(512), dim3(512), 0, stream>>>(query, value, W, bwl, gamma, beta, (float*)d_out);
}